// Round 2
// baseline (158.121 us; speedup 1.0000x reference)
//
#include <hip/hip_runtime.h>
#include <hip/hip_bf16.h>

#define NN 8192
#define DIN 256
#define DOUT 64

typedef __attribute__((ext_vector_type(4))) float f32x4;
typedef __attribute__((ext_vector_type(4))) int i32x4;
typedef __attribute__((ext_vector_type(8))) short short8;

__device__ __forceinline__ unsigned enc_f(float f) {
  unsigned u = __float_as_uint(f);
  return (u & 0x80000000u) ? ~u : (u | 0x80000000u);
}
__device__ __forceinline__ float dec_f(unsigned u) {
  return (u & 0x80000000u) ? __uint_as_float(u & 0x7fffffffu)
                           : __uint_as_float(~u);
}
__device__ __forceinline__ unsigned short f2bf(float f) {
  unsigned u = __float_as_uint(f);
  u += 0x7fffu + ((u >> 16) & 1u);
  return (unsigned short)(u >> 16);
}

__global__ void k_init(unsigned* dmax) { *dmax = 0u; }

// h = X@W (fp32), src = h@a[:64], dst = h@a[64:], dstmax, HT = bf16(h)^T [64][8192]
// 256 blocks x 32 rows, 1 row/thread, 8 d-cols/thread.
__global__ __launch_bounds__(256) void k_hw(
    const float* __restrict__ X, const float* __restrict__ W,
    const float* __restrict__ A, float* __restrict__ src,
    float* __restrict__ dst, unsigned* __restrict__ dmax,
    unsigned short* __restrict__ HT) {
  __shared__ float Wl[DIN * DOUT];  // 64 KB
  const int tid = threadIdx.x;
#pragma unroll
  for (int i = 0; i < 16; ++i)
    ((f32x4*)Wl)[tid + 256 * i] = ((const f32x4*)W)[tid + 256 * i];
  __syncthreads();
  const int q = tid & 7;
  const int row = blockIdx.x * 32 + (tid >> 3);
  float acc[8];
#pragma unroll
  for (int d = 0; d < 8; ++d) acc[d] = 0.f;
  const f32x4* __restrict__ Xr = (const f32x4*)(X + (size_t)row * DIN);
#pragma unroll 4
  for (int k4 = 0; k4 < DIN / 4; ++k4) {
    const f32x4 xv = Xr[k4];
#pragma unroll
    for (int kk = 0; kk < 4; ++kk) {
      const f32x4 w0 = *(const f32x4*)&Wl[(k4 * 4 + kk) * DOUT + q * 8];
      const f32x4 w1 = *(const f32x4*)&Wl[(k4 * 4 + kk) * DOUT + q * 8 + 4];
#pragma unroll
      for (int d = 0; d < 4; ++d) {
        acc[d] += xv[kk] * w0[d];
        acc[d + 4] += xv[kk] * w1[d];
      }
    }
  }
  const f32x4 as0 = *(const f32x4*)&A[q * 8];
  const f32x4 as1 = *(const f32x4*)&A[q * 8 + 4];
  const f32x4 ad0 = *(const f32x4*)&A[DOUT + q * 8];
  const f32x4 ad1 = *(const f32x4*)&A[DOUT + q * 8 + 4];
  float sv = 0.f, dv = 0.f;
#pragma unroll
  for (int e = 0; e < 4; ++e) {
    sv += acc[e] * as0[e] + acc[e + 4] * as1[e];
    dv += acc[e] * ad0[e] + acc[e + 4] * ad1[e];
  }
#pragma unroll
  for (int m = 1; m < 8; m <<= 1) {
    sv += __shfl_xor(sv, m);
    dv += __shfl_xor(dv, m);
  }
  if (q == 0) {
    src[row] = sv;
    dst[row] = dv;
  }
  float dm = dv;
#pragma unroll
  for (int m = 8; m < 64; m <<= 1) dm = fmaxf(dm, __shfl_xor(dm, m));
  if ((tid & 63) == 0) atomicMax(dmax, enc_f(dm));
#pragma unroll
  for (int d = 0; d < 8; ++d) HT[(size_t)(q * 8 + d) * NN + row] = f2bf(acc[d]);
}

// Fused masked-softmax-numerator @ H via MFMA; K-chunked partials.
// Wave tile: 16 rows x 64 d, streaming 32 j per step, adj prefetched 1 deep.
__global__ __launch_bounds__(256) void k_att(
    const int* __restrict__ adj, const float* __restrict__ src,
    const float* __restrict__ dst, const unsigned* __restrict__ dmax,
    const unsigned short* __restrict__ HT, float* __restrict__ pacc,
    float* __restrict__ ps, int nchunk) {
  const int tid = threadIdx.x;
  const int wid = tid >> 6, lane = tid & 63;
  const int rowtile = blockIdx.x * 64 + wid * 16;
  const int c = blockIdx.y;
  const int CL = NN / nchunk;
  const int jbeg = c * CL, jend = jbeg + CL;
  const int l15 = lane & 15, kc = lane >> 4;
  const int arow = rowtile + l15;
  const float srci = src[arow];
  const float dmx = dec_f(*dmax);
  const float e0 = srci + dmx;
  const float mi = fmaxf(e0, 0.2f * e0);  // upper bound of leakyrelu scores
  f32x4 acc0 = {0.f, 0.f, 0.f, 0.f};
  f32x4 acc1 = acc0, acc2 = acc0, acc3 = acc0;
  float sac = 0.f;
  const int* __restrict__ arp = adj + (size_t)arow * NN + kc * 8;
  const float* __restrict__ dp = dst + kc * 8;
  const unsigned short* __restrict__ hb = HT + (size_t)l15 * NN + kc * 8;
  i32x4 av0 = __builtin_nontemporal_load((const i32x4*)(arp + jbeg));
  i32x4 av1 = __builtin_nontemporal_load((const i32x4*)(arp + jbeg) + 1);
  for (int jt = jbeg; jt < jend; jt += 32) {
    const i32x4 cv0 = av0, cv1 = av1;
    const int jn = jt + 32;
    if (jn < jend) {
      av0 = __builtin_nontemporal_load((const i32x4*)(arp + jn));
      av1 = __builtin_nontemporal_load((const i32x4*)(arp + jn) + 1);
    }
    const f32x4 dd0 = *(const f32x4*)(dp + jt);
    const f32x4 dd1 = *(const f32x4*)(dp + jt + 4);
    short8 af;
#pragma unroll
    for (int e = 0; e < 8; ++e) {
      const int a = (e < 4) ? cv0[e] : cv1[e - 4];
      const float d = (e < 4) ? dd0[e] : dd1[e - 4];
      const float ee = srci + d;
      const float y = fmaxf(ee, 0.2f * ee);  // leakyrelu(0.2)
      const float pv = (a > 0) ? __expf(y - mi) : 0.f;
      sac += pv;
      af[e] = (short)f2bf(pv);
    }
    const short8 bf0 = *(const short8*)(hb + jt);
    const short8 bf1 = *(const short8*)(hb + 16 * NN + jt);
    const short8 bf2 = *(const short8*)(hb + 32 * NN + jt);
    const short8 bf3 = *(const short8*)(hb + 48 * NN + jt);
    acc0 = __builtin_amdgcn_mfma_f32_16x16x32_bf16(af, bf0, acc0, 0, 0, 0);
    acc1 = __builtin_amdgcn_mfma_f32_16x16x32_bf16(af, bf1, acc1, 0, 0, 0);
    acc2 = __builtin_amdgcn_mfma_f32_16x16x32_bf16(af, bf2, acc2, 0, 0, 0);
    acc3 = __builtin_amdgcn_mfma_f32_16x16x32_bf16(af, bf3, acc3, 0, 0, 0);
  }
  float st = sac;
  st += __shfl_xor(st, 16);
  st += __shfl_xor(st, 32);
  if (lane < 16) ps[(size_t)c * NN + arow] = st;
  const int orow = rowtile + kc * 4;  // C/D: col=lane&15, row=(lane>>4)*4+reg
  float* __restrict__ pb = pacc + ((size_t)c * NN + orow) * DOUT + l15;
#pragma unroll
  for (int v = 0; v < 4; ++v) {
    pb[(size_t)v * DOUT + 0] = acc0[v];
    pb[(size_t)v * DOUT + 16] = acc1[v];
    pb[(size_t)v * DOUT + 32] = acc2[v];
    pb[(size_t)v * DOUT + 48] = acc3[v];
  }
}

__global__ __launch_bounds__(256) void k_fin(const float* __restrict__ pacc,
                                             const float* __restrict__ ps,
                                             float* __restrict__ out,
                                             int nchunk) {
  const int idx = blockIdx.x * 256 + threadIdx.x;
  const int i = idx >> 6;
  float ss = 0.f, as = 0.f;
  for (int c = 0; c < nchunk; ++c) {
    ss += ps[(size_t)c * NN + i];
    as += pacc[(size_t)c * NN * DOUT + idx];
  }
  const float v = as / ss;
  out[idx] = v > 0.f ? v : (__expf(v) - 1.f);
}

extern "C" void kernel_launch(void* const* d_in, const int* in_sizes, int n_in,
                              void* d_out, int out_size, void* d_ws,
                              size_t ws_size, hipStream_t stream) {
  const float* X = (const float*)d_in[0];
  const int* adj = (const int*)d_in[1];
  const float* W = (const float*)d_in[2];
  const float* A = (const float*)d_in[3];
  float* out = (float*)d_out;
  char* ws = (char*)d_ws;
  float* src = (float*)(ws);
  float* dst = (float*)(ws + (32u << 10));
  unsigned* dmax = (unsigned*)(ws + (64u << 10));
  unsigned short* HT = (unsigned short*)(ws + (128u << 10));
  float* pacc = (float*)(ws + (2u << 20));
  int nchunk = 8;
  while (nchunk > 1 &&
         (size_t)(2u << 20) +
                 (size_t)nchunk * (size_t)(NN * DOUT + NN) * 4 >
             ws_size)
    nchunk >>= 1;
  float* ps = pacc + (size_t)nchunk * NN * DOUT;
  k_init<<<1, 1, 0, stream>>>(dmax);
  k_hw<<<NN / 32, 256, 0, stream>>>(X, W, A, src, dst, dmax, HT);
  k_att<<<dim3(NN / 64, nchunk), 256, 0, stream>>>(adj, src, dst, dmax, HT,
                                                   pacc, ps, nchunk);
  k_fin<<<NN * DOUT / 256, 256, 0, stream>>>(pacc, ps, out, nchunk);
}

// Round 3
// 126.047 us; speedup vs baseline: 1.2545x; 1.2545x over previous
//
#include <hip/hip_runtime.h>
#include <hip/hip_bf16.h>

#define NN 8192
#define DIN 256
#define DOUT 64
#define NCH 8

typedef __attribute__((ext_vector_type(4))) float f32x4;
typedef __attribute__((ext_vector_type(8))) short short8;

__device__ __forceinline__ unsigned enc_f(float f) {
  unsigned u = __float_as_uint(f);
  return (u & 0x80000000u) ? ~u : (u | 0x80000000u);
}
__device__ __forceinline__ float dec_f(unsigned u) {
  return (u & 0x80000000u) ? __uint_as_float(u & 0x7fffffffu)
                           : __uint_as_float(~u);
}
__device__ __forceinline__ unsigned short f2bf(float f) {
  unsigned u = __float_as_uint(f);
  u += 0x7fffu + ((u >> 16) & 1u);
  return (unsigned short)(u >> 16);
}
__device__ __forceinline__ unsigned pk2bf(float lo, float hi) {
  return (unsigned)f2bf(lo) | ((unsigned)f2bf(hi) << 16);
}

// dmax init + WTb[d][k] = bf16(W[k][d]); grid 64 x 256
__global__ __launch_bounds__(256) void k_prep(const float* __restrict__ W,
                                              unsigned short* __restrict__ WTb,
                                              unsigned* __restrict__ dmax) {
  const int i = blockIdx.x * 256 + threadIdx.x;
  if (i == 0) *dmax = 0u;
  const int d = i >> 8, k = i & 255;
  WTb[i] = f2bf(W[k * DOUT + d]);
}

// blocks [0,128): h=X@W via MFMA -> src/dst/dmax/HTt.  blocks [128,2176): bitpack adj.
__global__ __launch_bounds__(256) void k_hwpack(
    const float* __restrict__ X, const unsigned short* __restrict__ WTb,
    const float* __restrict__ A, const int* __restrict__ adj,
    float* __restrict__ src, float* __restrict__ dst,
    unsigned* __restrict__ dmax, unsigned short* __restrict__ HTt,
    unsigned long long* __restrict__ pk) {
  const int tid = threadIdx.x;
  const int wid = tid >> 6, lane = tid & 63;
  if (blockIdx.x >= 128) {
    // ---- pack: one adj row per wave, fully coalesced, ballot -> bitmask ----
    const int row = (blockIdx.x - 128) * 4 + wid;
    const int4* __restrict__ ap = (const int4*)(adj + (size_t)row * NN);
    unsigned long long* __restrict__ pr = pk + (size_t)row * 128;
#pragma unroll 2
    for (int g = 0; g < 32; ++g) {
      const int4 v = ap[g * 64 + lane];
      const unsigned long long b0 = __ballot(v.x > 0);
      const unsigned long long b1 = __ballot(v.y > 0);
      const unsigned long long b2 = __ballot(v.z > 0);
      const unsigned long long b3 = __ballot(v.w > 0);
      if (lane == 0) {
        pr[g * 4 + 0] = b0;
        pr[g * 4 + 1] = b1;
        pr[g * 4 + 2] = b2;
        pr[g * 4 + 3] = b3;
      }
    }
    return;
  }
  // ---- hw: 16 rows per wave via mfma 16x16x32 ----
  const int l15 = lane & 15, kc = lane >> 4;
  const int rt = blockIdx.x * 64 + wid * 16;
  const float* __restrict__ xr = X + (size_t)(rt + l15) * DIN + kc * 8;
  const unsigned short* __restrict__ wb = WTb + (size_t)l15 * DIN + kc * 8;
  f32x4 acc0 = {0.f, 0.f, 0.f, 0.f};
  f32x4 acc1 = acc0, acc2 = acc0, acc3 = acc0;
#pragma unroll
  for (int ks = 0; ks < 8; ++ks) {
    const f32x4 x0 = *(const f32x4*)(xr + ks * 32);
    const f32x4 x1 = *(const f32x4*)(xr + ks * 32 + 4);
    short8 af;
    ((unsigned*)&af)[0] = pk2bf(x0[0], x0[1]);
    ((unsigned*)&af)[1] = pk2bf(x0[2], x0[3]);
    ((unsigned*)&af)[2] = pk2bf(x1[0], x1[1]);
    ((unsigned*)&af)[3] = pk2bf(x1[2], x1[3]);
    const short8 b0 = *(const short8*)(wb + ks * 32);
    const short8 b1 = *(const short8*)(wb + 16 * DIN + ks * 32);
    const short8 b2 = *(const short8*)(wb + 32 * DIN + ks * 32);
    const short8 b3 = *(const short8*)(wb + 48 * DIN + ks * 32);
    acc0 = __builtin_amdgcn_mfma_f32_16x16x32_bf16(af, b0, acc0, 0, 0, 0);
    acc1 = __builtin_amdgcn_mfma_f32_16x16x32_bf16(af, b1, acc1, 0, 0, 0);
    acc2 = __builtin_amdgcn_mfma_f32_16x16x32_bf16(af, b2, acc2, 0, 0, 0);
    acc3 = __builtin_amdgcn_mfma_f32_16x16x32_bf16(af, b3, acc3, 0, 0, 0);
  }
  // src/dst dots from fp32 accumulators; C/D: col=lane&15, row=kc*4+v
  const float as0 = A[l15], as1 = A[16 + l15], as2 = A[32 + l15],
              as3 = A[48 + l15];
  const float ad0 = A[64 + l15], ad1 = A[80 + l15], ad2 = A[96 + l15],
              ad3 = A[112 + l15];
  float dm = -1e30f;
#pragma unroll
  for (int v = 0; v < 4; ++v) {
    float sv = acc0[v] * as0 + acc1[v] * as1 + acc2[v] * as2 + acc3[v] * as3;
    float dv = acc0[v] * ad0 + acc1[v] * ad1 + acc2[v] * ad2 + acc3[v] * ad3;
#pragma unroll
    for (int m = 1; m < 16; m <<= 1) {
      sv += __shfl_xor(sv, m);
      dv += __shfl_xor(dv, m);
    }
    if (l15 == 0) {
      src[rt + kc * 4 + v] = sv;
      dst[rt + kc * 4 + v] = dv;
    }
    dm = fmaxf(dm, dv);
  }
  dm = fmaxf(dm, __shfl_xor(dm, 16));
  dm = fmaxf(dm, __shfl_xor(dm, 32));
  if (lane == 0) atomicMax(dmax, enc_f(dm));
  // HTt[jb][n][l15][jin] = bf16(h[jb*32+jin][n*16+l15])
  unsigned short* __restrict__ hs =
      HTt + (size_t)(rt >> 5) * 2048 + l15 * 32 + (rt & 16) + kc * 4;
  *(unsigned*)(hs + 0 * 512) = pk2bf(acc0[0], acc0[1]);
  *(unsigned*)(hs + 0 * 512 + 2) = pk2bf(acc0[2], acc0[3]);
  *(unsigned*)(hs + 1 * 512) = pk2bf(acc1[0], acc1[1]);
  *(unsigned*)(hs + 1 * 512 + 2) = pk2bf(acc1[2], acc1[3]);
  *(unsigned*)(hs + 2 * 512) = pk2bf(acc2[0], acc2[1]);
  *(unsigned*)(hs + 2 * 512 + 2) = pk2bf(acc2[2], acc2[3]);
  *(unsigned*)(hs + 3 * 512) = pk2bf(acc3[0], acc3[1]);
  *(unsigned*)(hs + 3 * 512 + 2) = pk2bf(acc3[2], acc3[3]);
}

// Fused masked-softmax-numerator @ H via MFMA on packed adj bits.
__global__ __launch_bounds__(256) void k_att(
    const unsigned long long* __restrict__ pk, const float* __restrict__ src,
    const float* __restrict__ dst, const unsigned* __restrict__ dmax,
    const unsigned short* __restrict__ HTt, float* __restrict__ pacc,
    float* __restrict__ ps) {
  const int tid = threadIdx.x;
  const int wid = tid >> 6, lane = tid & 63;
  const int l15 = lane & 15, kc = lane >> 4;
  const int rowtile = blockIdx.x * 64 + wid * 16;
  const int c = blockIdx.y;
  const int arow = rowtile + l15;
  const float srci = src[arow];
  const float dmx = dec_f(*dmax);
  const float e0 = srci + dmx;
  const float mi = fmaxf(e0, 0.2f * e0);  // upper bound of leakyrelu scores
  f32x4 acc0 = {0.f, 0.f, 0.f, 0.f};
  f32x4 acc1 = acc0, acc2 = acc0, acc3 = acc0;
  float sac = 0.f;
  const unsigned long long* __restrict__ pr = pk + (size_t)arow * 128;
  const float* __restrict__ dp = dst + kc * 8;
  const unsigned short* __restrict__ hb = HTt + kc * 8 + l15 * 32;
  const int g0 = c * (32 / NCH);
  for (int g = g0; g < g0 + 32 / NCH; ++g) {
    const unsigned long long b0 = pr[g * 4 + 0];
    const unsigned long long b1 = pr[g * 4 + 1];
    const unsigned long long b2 = pr[g * 4 + 2];
    const unsigned long long b3 = pr[g * 4 + 3];
#pragma unroll
    for (int s = 0; s < 8; ++s) {
      const int jt = g * 256 + s * 32;
      const int q = s * 8 + kc * 2;
      const unsigned sh0 = (unsigned)(b0 >> q);
      const unsigned sh1 = (unsigned)(b1 >> q);
      const unsigned sh2 = (unsigned)(b2 >> q);
      const unsigned sh3 = (unsigned)(b3 >> q);
      const f32x4 dd0 = *(const f32x4*)(dp + jt);
      const f32x4 dd1 = *(const f32x4*)(dp + jt + 4);
      float pv[8];
#pragma unroll
      for (int e = 0; e < 8; ++e) {
        const float d = (e < 4) ? dd0[e & 3] : dd1[e & 3];
        const float ee = srci + d;
        const float y = fmaxf(ee, 0.2f * ee);  // leakyrelu(0.2)
        const float ex = __expf(y - mi);
        const unsigned shv = (e == 0 || e == 4)   ? sh0
                             : (e == 1 || e == 5) ? sh1
                             : (e == 2 || e == 6) ? sh2
                                                  : sh3;
        const unsigned bit = (shv >> (e >> 2)) & 1u;
        const float pvv = bit ? ex : 0.f;
        sac += pvv;
        pv[e] = pvv;
      }
      short8 af;
      ((unsigned*)&af)[0] = pk2bf(pv[0], pv[1]);
      ((unsigned*)&af)[1] = pk2bf(pv[2], pv[3]);
      ((unsigned*)&af)[2] = pk2bf(pv[4], pv[5]);
      ((unsigned*)&af)[3] = pk2bf(pv[6], pv[7]);
      const unsigned short* hj = hb + (size_t)jt * 64;
      const short8 bf0 = *(const short8*)(hj);
      const short8 bf1 = *(const short8*)(hj + 512);
      const short8 bf2 = *(const short8*)(hj + 1024);
      const short8 bf3 = *(const short8*)(hj + 1536);
      acc0 = __builtin_amdgcn_mfma_f32_16x16x32_bf16(af, bf0, acc0, 0, 0, 0);
      acc1 = __builtin_amdgcn_mfma_f32_16x16x32_bf16(af, bf1, acc1, 0, 0, 0);
      acc2 = __builtin_amdgcn_mfma_f32_16x16x32_bf16(af, bf2, acc2, 0, 0, 0);
      acc3 = __builtin_amdgcn_mfma_f32_16x16x32_bf16(af, bf3, acc3, 0, 0, 0);
    }
  }
  float st = sac;
  st += __shfl_xor(st, 16);
  st += __shfl_xor(st, 32);
  if (lane < 16) ps[(size_t)c * NN + arow] = st;
  const int orow = rowtile + kc * 4;  // C/D: col=lane&15, row=kc*4+v
  float* __restrict__ pb = pacc + ((size_t)c * NN + orow) * DOUT + l15;
#pragma unroll
  for (int v = 0; v < 4; ++v) {
    pb[(size_t)v * DOUT + 0] = acc0[v];
    pb[(size_t)v * DOUT + 16] = acc1[v];
    pb[(size_t)v * DOUT + 32] = acc2[v];
    pb[(size_t)v * DOUT + 48] = acc3[v];
  }
}

__global__ __launch_bounds__(256) void k_fin(const float* __restrict__ pacc,
                                             const float* __restrict__ ps,
                                             float* __restrict__ out) {
  const int idx = blockIdx.x * 256 + threadIdx.x;
  const int i = idx >> 6;
  float ss = 0.f, as = 0.f;
#pragma unroll
  for (int c = 0; c < NCH; ++c) {
    ss += ps[(size_t)c * NN + i];
    as += pacc[(size_t)c * NN * DOUT + idx];
  }
  const float v = as / ss;
  out[idx] = v > 0.f ? v : (__expf(v) - 1.f);
}

extern "C" void kernel_launch(void* const* d_in, const int* in_sizes, int n_in,
                              void* d_out, int out_size, void* d_ws,
                              size_t ws_size, hipStream_t stream) {
  const float* X = (const float*)d_in[0];
  const int* adj = (const int*)d_in[1];
  const float* W = (const float*)d_in[2];
  const float* A = (const float*)d_in[3];
  float* out = (float*)d_out;
  char* ws = (char*)d_ws;
  float* src = (float*)(ws);                              // 32 KB
  float* dst = (float*)(ws + (32u << 10));                // 32 KB
  unsigned* dmax = (unsigned*)(ws + (64u << 10));         // 4 B
  unsigned short* WTb = (unsigned short*)(ws + (128u << 10));  // 32 KB
  unsigned short* HTt = (unsigned short*)(ws + (256u << 10));  // 1 MB
  unsigned long long* pkb = (unsigned long long*)(ws + (2u << 20));  // 8 MB
  float* pacc = (float*)(ws + (16u << 20));               // NCH*2 MB
  float* ps = pacc + (size_t)NCH * NN * DOUT;             // NCH*32 KB
  k_prep<<<64, 256, 0, stream>>>(W, WTb, dmax);
  k_hwpack<<<128 + NN / 4, 256, 0, stream>>>(X, WTb, A, adj, src, dst, dmax,
                                             HTt, pkb);
  k_att<<<dim3(NN / 64, NCH), 256, 0, stream>>>(pkb, src, dst, dmax, HTt, pacc,
                                                ps);
  k_fin<<<NN * DOUT / 256, 256, 0, stream>>>(pacc, ps, out);
}

// Round 5
// 121.302 us; speedup vs baseline: 1.3035x; 1.0391x over previous
//
#include <hip/hip_runtime.h>
#include <hip/hip_bf16.h>

#define NN 8192
#define DIN 256
#define DOUT 64
#define NCH 16
#define CHJ (NN / NCH)  // 512

typedef __attribute__((ext_vector_type(4))) float f32x4;
typedef __attribute__((ext_vector_type(4))) int i32x4;
typedef __attribute__((ext_vector_type(8))) short short8;
typedef __attribute__((ext_vector_type(2))) unsigned long long u64x2;

__device__ __forceinline__ unsigned enc_f(float f) {
  unsigned u = __float_as_uint(f);
  return (u & 0x80000000u) ? ~u : (u | 0x80000000u);
}
__device__ __forceinline__ float dec_f(unsigned u) {
  return (u & 0x80000000u) ? __uint_as_float(u & 0x7fffffffu)
                           : __uint_as_float(~u);
}
__device__ __forceinline__ unsigned short f2bf(float f) {
  unsigned u = __float_as_uint(f);
  u += 0x7fffu + ((u >> 16) & 1u);
  return (unsigned short)(u >> 16);
}
__device__ __forceinline__ unsigned pk2bf(float lo, float hi) {
  return (unsigned)f2bf(lo) | ((unsigned)f2bf(hi) << 16);
}
__device__ __forceinline__ unsigned cvtpk(float lo, float hi) {
  unsigned r;
  asm("v_cvt_pk_bf16_f32 %0, %1, %2" : "=v"(r) : "v"(lo), "v"(hi));
  return r;
}

// dmax init + WTb[d][k] = bf16(W[k][d]); grid 64 x 256
__global__ __launch_bounds__(256) void k_prep(const float* __restrict__ W,
                                              unsigned short* __restrict__ WTb,
                                              unsigned* __restrict__ dmax) {
  const int i = blockIdx.x * 256 + threadIdx.x;
  if (i == 0) *dmax = 0u;
  const int d = i >> 8, k = i & 255;
  WTb[i] = f2bf(W[k * DOUT + d]);
}

// blocks [0,128): h=X@W via MFMA -> src/dst/dmax/HTt.  blocks [128,2176): bitpack adj.
__global__ __launch_bounds__(256) void k_hwpack(
    const float* __restrict__ X, const unsigned short* __restrict__ WTb,
    const float* __restrict__ A, const int* __restrict__ adj,
    float* __restrict__ src, float* __restrict__ dst,
    unsigned* __restrict__ dmax, unsigned short* __restrict__ HTt,
    unsigned long long* __restrict__ pk) {
  const int tid = threadIdx.x;
  const int wid = tid >> 6, lane = tid & 63;
  if (blockIdx.x >= 128) {
    // ---- pack: one adj row per wave; word w = i*8 + (j&7), bit = (j>>3)&63
    const int row = (blockIdx.x - 128) * 4 + wid;
    const i32x4* __restrict__ ap = (const i32x4*)(adj + (size_t)row * NN);
    unsigned long long* __restrict__ pr = pk + (size_t)row * 128;
#pragma unroll 4
    for (int i = 0; i < 16; ++i) {
      const i32x4 v0 = __builtin_nontemporal_load(ap + i * 128 + lane * 2);
      const i32x4 v1 = __builtin_nontemporal_load(ap + i * 128 + lane * 2 + 1);
      const unsigned long long b0 = __ballot(v0[0] > 0);
      const unsigned long long b1 = __ballot(v0[1] > 0);
      const unsigned long long b2 = __ballot(v0[2] > 0);
      const unsigned long long b3 = __ballot(v0[3] > 0);
      const unsigned long long b4 = __ballot(v1[0] > 0);
      const unsigned long long b5 = __ballot(v1[1] > 0);
      const unsigned long long b6 = __ballot(v1[2] > 0);
      const unsigned long long b7 = __ballot(v1[3] > 0);
      if (lane == 0) {
        u64x2 s0, s1, s2, s3;
        s0[0] = b0; s0[1] = b1; s1[0] = b2; s1[1] = b3;
        s2[0] = b4; s2[1] = b5; s3[0] = b6; s3[1] = b7;
        *(u64x2*)(pr + i * 8 + 0) = s0;
        *(u64x2*)(pr + i * 8 + 2) = s1;
        *(u64x2*)(pr + i * 8 + 4) = s2;
        *(u64x2*)(pr + i * 8 + 6) = s3;
      }
    }
    return;
  }
  // ---- hw: 16 rows per wave via mfma 16x16x32 ----
  const int l15 = lane & 15, kc = lane >> 4;
  const int rt = blockIdx.x * 64 + wid * 16;
  const float* __restrict__ xr = X + (size_t)(rt + l15) * DIN + kc * 8;
  const unsigned short* __restrict__ wb = WTb + (size_t)l15 * DIN + kc * 8;
  f32x4 acc0 = {0.f, 0.f, 0.f, 0.f};
  f32x4 acc1 = acc0, acc2 = acc0, acc3 = acc0;
#pragma unroll
  for (int ks = 0; ks < 8; ++ks) {
    const f32x4 x0 = *(const f32x4*)(xr + ks * 32);
    const f32x4 x1 = *(const f32x4*)(xr + ks * 32 + 4);
    short8 af;
    ((unsigned*)&af)[0] = pk2bf(x0[0], x0[1]);
    ((unsigned*)&af)[1] = pk2bf(x0[2], x0[3]);
    ((unsigned*)&af)[2] = pk2bf(x1[0], x1[1]);
    ((unsigned*)&af)[3] = pk2bf(x1[2], x1[3]);
    const short8 b0 = *(const short8*)(wb + ks * 32);
    const short8 b1 = *(const short8*)(wb + 16 * DIN + ks * 32);
    const short8 b2 = *(const short8*)(wb + 32 * DIN + ks * 32);
    const short8 b3 = *(const short8*)(wb + 48 * DIN + ks * 32);
    acc0 = __builtin_amdgcn_mfma_f32_16x16x32_bf16(af, b0, acc0, 0, 0, 0);
    acc1 = __builtin_amdgcn_mfma_f32_16x16x32_bf16(af, b1, acc1, 0, 0, 0);
    acc2 = __builtin_amdgcn_mfma_f32_16x16x32_bf16(af, b2, acc2, 0, 0, 0);
    acc3 = __builtin_amdgcn_mfma_f32_16x16x32_bf16(af, b3, acc3, 0, 0, 0);
  }
  const float as0 = A[l15], as1 = A[16 + l15], as2 = A[32 + l15],
              as3 = A[48 + l15];
  const float ad0 = A[64 + l15], ad1 = A[80 + l15], ad2 = A[96 + l15],
              ad3 = A[112 + l15];
  float dm = -1e30f;
#pragma unroll
  for (int v = 0; v < 4; ++v) {
    float sv = acc0[v] * as0 + acc1[v] * as1 + acc2[v] * as2 + acc3[v] * as3;
    float dv = acc0[v] * ad0 + acc1[v] * ad1 + acc2[v] * ad2 + acc3[v] * ad3;
#pragma unroll
    for (int m = 1; m < 16; m <<= 1) {
      sv += __shfl_xor(sv, m);
      dv += __shfl_xor(dv, m);
    }
    if (l15 == 0) {
      src[rt + kc * 4 + v] = sv;
      dst[rt + kc * 4 + v] = dv;
    }
    dm = fmaxf(dm, dv);
  }
  dm = fmaxf(dm, __shfl_xor(dm, 16));
  dm = fmaxf(dm, __shfl_xor(dm, 32));
  if (lane == 0) atomicMax(dmax, enc_f(dm));
  // HTt[jb][n][l15][jin] = bf16(h[jb*32+jin][n*16+l15])
  unsigned short* __restrict__ hs =
      HTt + (size_t)(rt >> 5) * 2048 + l15 * 32 + (rt & 16) + kc * 4;
  *(unsigned*)(hs + 0 * 512) = pk2bf(acc0[0], acc0[1]);
  *(unsigned*)(hs + 0 * 512 + 2) = pk2bf(acc0[2], acc0[3]);
  *(unsigned*)(hs + 1 * 512) = pk2bf(acc1[0], acc1[1]);
  *(unsigned*)(hs + 1 * 512 + 2) = pk2bf(acc1[2], acc1[3]);
  *(unsigned*)(hs + 2 * 512) = pk2bf(acc2[0], acc2[1]);
  *(unsigned*)(hs + 2 * 512 + 2) = pk2bf(acc2[2], acc2[3]);
  *(unsigned*)(hs + 3 * 512) = pk2bf(acc3[0], acc3[1]);
  *(unsigned*)(hs + 3 * 512 + 2) = pk2bf(acc3[2], acc3[3]);
}

// Fused masked-softmax-numerator @ H via MFMA on packed bits; exp via E-tables.
__global__ __launch_bounds__(256) void k_att(
    const unsigned long long* __restrict__ pk, const float* __restrict__ src,
    const float* __restrict__ dst, const unsigned* __restrict__ dmax,
    const unsigned short* __restrict__ HTt, float* __restrict__ pacc,
    float* __restrict__ ps) {
  __shared__ float E1s[CHJ], E2s[CHJ];
  const int tid = threadIdx.x;
  const int wid = tid >> 6, lane = tid & 63;
  const int l15 = lane & 15, kc = lane >> 4;
  const int rowtile = blockIdx.x * 64 + wid * 16;
  const int c = blockIdx.y;
  const int cbase = c * CHJ;
  {
    const float2 dv2 = *(const float2*)(dst + cbase + tid * 2);
    E1s[tid * 2] = __expf(dv2.x);
    E1s[tid * 2 + 1] = __expf(dv2.y);
    E2s[tid * 2] = __expf(0.2f * dv2.x);
    E2s[tid * 2 + 1] = __expf(0.2f * dv2.y);
  }
  __syncthreads();
  const int arow = rowtile + l15;
  const float srci = src[arow];
  const float dmx = dec_f(*dmax);
  const float e0 = srci + dmx;
  const float mi = fmaxf(e0, 0.2f * e0);  // upper bound of leakyrelu scores
  const float cA = __expf(srci - mi);
  const float cB = __expf(0.2f * srci - mi);
  // 8 mask words for this row/chunk; pre-shift by kc so bit (s*4) is ours.
  unsigned bl[8], bh[8];
  {
    const unsigned long long* __restrict__ pr =
        pk + (size_t)arow * 128 + c * 8;
    const u64x2 m0 = *(const u64x2*)(pr + 0);
    const u64x2 m1 = *(const u64x2*)(pr + 2);
    const u64x2 m2 = *(const u64x2*)(pr + 4);
    const u64x2 m3 = *(const u64x2*)(pr + 6);
    const unsigned long long mw[8] = {m0[0], m0[1], m1[0], m1[1],
                                      m2[0], m2[1], m3[0], m3[1]};
#pragma unroll
    for (int e = 0; e < 8; ++e) {
      const unsigned long long sh = mw[e] >> kc;
      bl[e] = (unsigned)sh;
      bh[e] = (unsigned)(sh >> 32);
    }
  }
  f32x4 acc0 = {0.f, 0.f, 0.f, 0.f};
  f32x4 acc1 = acc0, acc2 = acc0, acc3 = acc0;
  float sac = 0.f;
  const unsigned short* __restrict__ hb =
      HTt + (size_t)(cbase >> 5) * 2048 + l15 * 32 + kc * 8;
#pragma unroll
  for (int s = 0; s < 16; ++s) {
    const int jr = s * 32 + kc * 8;
    const f32x4 e1a = *(const f32x4*)&E1s[jr];
    const f32x4 e1b = *(const f32x4*)&E1s[jr + 4];
    const f32x4 e2a = *(const f32x4*)&E2s[jr];
    const f32x4 e2b = *(const f32x4*)&E2s[jr + 4];
    float pv[8];
#pragma unroll
    for (int e = 0; e < 8; ++e) {
      const float E1v = (e < 4) ? e1a[e & 3] : e1b[e & 3];
      const float E2v = (e < 4) ? e2a[e & 3] : e2b[e & 3];
      float p = fmaxf(cA * E1v, cB * E2v);  // exp(leaky(src+dst)-mi)
      const unsigned w = (s < 8) ? bl[e] : bh[e];
      const unsigned bit = (w >> ((s & 7) * 4)) & 1u;
      p = bit ? p : 0.f;
      sac += p;
      pv[e] = p;
    }
    short8 af;
    ((unsigned*)&af)[0] = cvtpk(pv[0], pv[1]);
    ((unsigned*)&af)[1] = cvtpk(pv[2], pv[3]);
    ((unsigned*)&af)[2] = cvtpk(pv[4], pv[5]);
    ((unsigned*)&af)[3] = cvtpk(pv[6], pv[7]);
    const unsigned short* hj = hb + (size_t)s * 2048;
    const short8 bf0 = *(const short8*)(hj);
    const short8 bf1 = *(const short8*)(hj + 512);
    const short8 bf2 = *(const short8*)(hj + 1024);
    const short8 bf3 = *(const short8*)(hj + 1536);
    acc0 = __builtin_amdgcn_mfma_f32_16x16x32_bf16(af, bf0, acc0, 0, 0, 0);
    acc1 = __builtin_amdgcn_mfma_f32_16x16x32_bf16(af, bf1, acc1, 0, 0, 0);
    acc2 = __builtin_amdgcn_mfma_f32_16x16x32_bf16(af, bf2, acc2, 0, 0, 0);
    acc3 = __builtin_amdgcn_mfma_f32_16x16x32_bf16(af, bf3, acc3, 0, 0, 0);
  }
  float st = sac;
  st += __shfl_xor(st, 16);
  st += __shfl_xor(st, 32);
  if (lane < 16) ps[(size_t)c * NN + arow] = st;
  const int orow = rowtile + kc * 4;  // C/D: col=lane&15, row=kc*4+v
  float* __restrict__ pb = pacc + ((size_t)c * NN + orow) * DOUT + l15;
#pragma unroll
  for (int v = 0; v < 4; ++v) {
    pb[(size_t)v * DOUT + 0] = acc0[v];
    pb[(size_t)v * DOUT + 16] = acc1[v];
    pb[(size_t)v * DOUT + 32] = acc2[v];
    pb[(size_t)v * DOUT + 48] = acc3[v];
  }
}

__global__ __launch_bounds__(256) void k_fin(const float* __restrict__ pacc,
                                             const float* __restrict__ ps,
                                             float* __restrict__ out) {
  const int idx = blockIdx.x * 256 + threadIdx.x;
  const int i = idx >> 6;
  float ss = 0.f, as = 0.f;
#pragma unroll
  for (int c = 0; c < NCH; ++c) {
    ss += ps[(size_t)c * NN + i];
    as += pacc[(size_t)c * NN * DOUT + idx];
  }
  const float v = as / ss;
  out[idx] = v > 0.f ? v : (__expf(v) - 1.f);
}

extern "C" void kernel_launch(void* const* d_in, const int* in_sizes, int n_in,
                              void* d_out, int out_size, void* d_ws,
                              size_t ws_size, hipStream_t stream) {
  const float* X = (const float*)d_in[0];
  const int* adj = (const int*)d_in[1];
  const float* W = (const float*)d_in[2];
  const float* A = (const float*)d_in[3];
  float* out = (float*)d_out;
  char* ws = (char*)d_ws;
  float* src = (float*)(ws);                                   // 32 KB
  float* dst = (float*)(ws + (32u << 10));                     // 32 KB
  unsigned* dmax = (unsigned*)(ws + (64u << 10));              // 4 B
  unsigned short* WTb = (unsigned short*)(ws + (128u << 10));  // 32 KB
  unsigned short* HTt = (unsigned short*)(ws + (256u << 10));  // 1 MB
  unsigned long long* pkb = (unsigned long long*)(ws + (2u << 20));  // 8 MB
  float* pacc = (float*)(ws + (16u << 20));  // NCH*2 MB = 32 MB
  float* ps = pacc + (size_t)NCH * NN * DOUT;  // NCH*32 KB
  k_prep<<<64, 256, 0, stream>>>(W, WTb, dmax);
  k_hwpack<<<128 + NN / 4, 256, 0, stream>>>(X, WTb, A, adj, src, dst, dmax,
                                             HTt, pkb);
  k_att<<<dim3(NN / 64, NCH), 256, 0, stream>>>(pkb, src, dst, dmax, HTt, pacc,
                                                ps);
  k_fin<<<NN * DOUT / 256, 256, 0, stream>>>(pacc, ps, out);
}

// Round 6
// 118.960 us; speedup vs baseline: 1.3292x; 1.0197x over previous
//
#include <hip/hip_runtime.h>
#include <hip/hip_bf16.h>

#define NN 8192
#define DIN 256
#define DOUT 64
#define NCH 16
#define CHJ (NN / NCH)  // 512

typedef __attribute__((ext_vector_type(4))) float f32x4;
typedef __attribute__((ext_vector_type(4))) int i32x4;
typedef __attribute__((ext_vector_type(8))) short short8;
typedef __attribute__((ext_vector_type(2))) unsigned long long u64x2;

__device__ __forceinline__ unsigned short f2bf(float f) {
  unsigned u = __float_as_uint(f);
  u += 0x7fffu + ((u >> 16) & 1u);
  return (unsigned short)(u >> 16);
}
__device__ __forceinline__ unsigned pk2bf(float lo, float hi) {
  return (unsigned)f2bf(lo) | ((unsigned)f2bf(hi) << 16);
}
__device__ __forceinline__ unsigned cvtpk(float lo, float hi) {
  unsigned r;
  asm("v_cvt_pk_bf16_f32 %0, %1, %2" : "=v"(r) : "v"(lo), "v"(hi));
  return r;
}

// WTb[d][k] = bf16(W[k][d]); grid 64 x 256
__global__ __launch_bounds__(256) void k_prep(const float* __restrict__ W,
                                              unsigned short* __restrict__ WTb) {
  const int i = blockIdx.x * 256 + threadIdx.x;
  const int d = i >> 8, k = i & 255;
  WTb[i] = f2bf(W[k * DOUT + d]);
}

// blocks [0,128): h=X@W via MFMA -> src/dst/dmax_arr/HTt. blocks [128,2176): bitpack adj.
__global__ __launch_bounds__(256) void k_hwpack(
    const float* __restrict__ X, const unsigned short* __restrict__ WTb,
    const float* __restrict__ A, const int* __restrict__ adj,
    float* __restrict__ src, float* __restrict__ dst,
    float* __restrict__ dmax_arr, unsigned short* __restrict__ HTt,
    unsigned long long* __restrict__ pk) {
  const int tid = threadIdx.x;
  const int wid = tid >> 6, lane = tid & 63;
  if (blockIdx.x >= 128) {
    // ---- pack: one adj row per wave; word w = i*8 + (j&7), bit = (j>>3)&63
    const int row = (blockIdx.x - 128) * 4 + wid;
    const i32x4* __restrict__ ap = (const i32x4*)(adj + (size_t)row * NN);
    unsigned long long* __restrict__ pr = pk + (size_t)row * 128;
#pragma unroll 4
    for (int i = 0; i < 16; ++i) {
      const i32x4 v0 = __builtin_nontemporal_load(ap + i * 128 + lane * 2);
      const i32x4 v1 = __builtin_nontemporal_load(ap + i * 128 + lane * 2 + 1);
      const unsigned long long b0 = __ballot(v0[0] > 0);
      const unsigned long long b1 = __ballot(v0[1] > 0);
      const unsigned long long b2 = __ballot(v0[2] > 0);
      const unsigned long long b3 = __ballot(v0[3] > 0);
      const unsigned long long b4 = __ballot(v1[0] > 0);
      const unsigned long long b5 = __ballot(v1[1] > 0);
      const unsigned long long b6 = __ballot(v1[2] > 0);
      const unsigned long long b7 = __ballot(v1[3] > 0);
      if (lane == 0) {
        u64x2 s0, s1, s2, s3;
        s0[0] = b0; s0[1] = b1; s1[0] = b2; s1[1] = b3;
        s2[0] = b4; s2[1] = b5; s3[0] = b6; s3[1] = b7;
        *(u64x2*)(pr + i * 8 + 0) = s0;
        *(u64x2*)(pr + i * 8 + 2) = s1;
        *(u64x2*)(pr + i * 8 + 4) = s2;
        *(u64x2*)(pr + i * 8 + 6) = s3;
      }
    }
    return;
  }
  // ---- hw: 16 rows per wave via mfma 16x16x32 ----
  const int l15 = lane & 15, kc = lane >> 4;
  const int rt = blockIdx.x * 64 + wid * 16;
  const float* __restrict__ xr = X + (size_t)(rt + l15) * DIN + kc * 8;
  const unsigned short* __restrict__ wb = WTb + (size_t)l15 * DIN + kc * 8;
  f32x4 acc0 = {0.f, 0.f, 0.f, 0.f};
  f32x4 acc1 = acc0, acc2 = acc0, acc3 = acc0;
#pragma unroll
  for (int ks = 0; ks < 8; ++ks) {
    const f32x4 x0 = *(const f32x4*)(xr + ks * 32);
    const f32x4 x1 = *(const f32x4*)(xr + ks * 32 + 4);
    short8 af;
    ((unsigned*)&af)[0] = pk2bf(x0[0], x0[1]);
    ((unsigned*)&af)[1] = pk2bf(x0[2], x0[3]);
    ((unsigned*)&af)[2] = pk2bf(x1[0], x1[1]);
    ((unsigned*)&af)[3] = pk2bf(x1[2], x1[3]);
    const short8 b0 = *(const short8*)(wb + ks * 32);
    const short8 b1 = *(const short8*)(wb + 16 * DIN + ks * 32);
    const short8 b2 = *(const short8*)(wb + 32 * DIN + ks * 32);
    const short8 b3 = *(const short8*)(wb + 48 * DIN + ks * 32);
    acc0 = __builtin_amdgcn_mfma_f32_16x16x32_bf16(af, b0, acc0, 0, 0, 0);
    acc1 = __builtin_amdgcn_mfma_f32_16x16x32_bf16(af, b1, acc1, 0, 0, 0);
    acc2 = __builtin_amdgcn_mfma_f32_16x16x32_bf16(af, b2, acc2, 0, 0, 0);
    acc3 = __builtin_amdgcn_mfma_f32_16x16x32_bf16(af, b3, acc3, 0, 0, 0);
  }
  const float as0 = A[l15], as1 = A[16 + l15], as2 = A[32 + l15],
              as3 = A[48 + l15];
  const float ad0 = A[64 + l15], ad1 = A[80 + l15], ad2 = A[96 + l15],
              ad3 = A[112 + l15];
  float dm = -1e30f;
#pragma unroll
  for (int v = 0; v < 4; ++v) {
    float sv = acc0[v] * as0 + acc1[v] * as1 + acc2[v] * as2 + acc3[v] * as3;
    float dv = acc0[v] * ad0 + acc1[v] * ad1 + acc2[v] * ad2 + acc3[v] * ad3;
#pragma unroll
    for (int m = 1; m < 16; m <<= 1) {
      sv += __shfl_xor(sv, m);
      dv += __shfl_xor(dv, m);
    }
    if (l15 == 0) {
      src[rt + kc * 4 + v] = sv;
      dst[rt + kc * 4 + v] = dv;
    }
    dm = fmaxf(dm, dv);
  }
  dm = fmaxf(dm, __shfl_xor(dm, 16));
  dm = fmaxf(dm, __shfl_xor(dm, 32));
  if (lane == 0) dmax_arr[blockIdx.x * 4 + wid] = dm;
  // HTt[jb][n][l15][jin] = bf16(h[jb*32+jin][n*16+l15])
  unsigned short* __restrict__ hs =
      HTt + (size_t)(rt >> 5) * 2048 + l15 * 32 + (rt & 16) + kc * 4;
  *(unsigned*)(hs + 0 * 512) = pk2bf(acc0[0], acc0[1]);
  *(unsigned*)(hs + 0 * 512 + 2) = pk2bf(acc0[2], acc0[3]);
  *(unsigned*)(hs + 1 * 512) = pk2bf(acc1[0], acc1[1]);
  *(unsigned*)(hs + 1 * 512 + 2) = pk2bf(acc1[2], acc1[3]);
  *(unsigned*)(hs + 2 * 512) = pk2bf(acc2[0], acc2[1]);
  *(unsigned*)(hs + 2 * 512 + 2) = pk2bf(acc2[2], acc2[3]);
  *(unsigned*)(hs + 3 * 512) = pk2bf(acc3[0], acc3[1]);
  *(unsigned*)(hs + 3 * 512 + 2) = pk2bf(acc3[2], acc3[3]);
}

// Fused masked-softmax-numerator @ H via MFMA on packed bits; exp via E-tables.
__global__ __launch_bounds__(256) void k_att(
    const unsigned long long* __restrict__ pk, const float* __restrict__ src,
    const float* __restrict__ dst, const float* __restrict__ dmax_arr,
    const unsigned short* __restrict__ HTt, float* __restrict__ pacc,
    float* __restrict__ ps) {
  __shared__ float E1s[CHJ], E2s[CHJ];
  __shared__ float dsm[4];
  const int tid = threadIdx.x;
  const int wid = tid >> 6, lane = tid & 63;
  const int l15 = lane & 15, kc = lane >> 4;
  const int rowtile = blockIdx.x * 64 + wid * 16;
  const int c = blockIdx.y;
  const int cbase = c * CHJ;
  {
    const float2 dv2 = *(const float2*)(dst + cbase + tid * 2);
    E1s[tid * 2] = __expf(dv2.x);
    E1s[tid * 2 + 1] = __expf(dv2.y);
    E2s[tid * 2] = __expf(0.2f * dv2.x);
    E2s[tid * 2 + 1] = __expf(0.2f * dv2.y);
    float dm0 = fmaxf(dmax_arr[tid], dmax_arr[tid + 256]);
#pragma unroll
    for (int m = 1; m < 64; m <<= 1) dm0 = fmaxf(dm0, __shfl_xor(dm0, m));
    if (lane == 0) dsm[wid] = dm0;
  }
  __syncthreads();
  const int arow = rowtile + l15;
  const float srci = src[arow];
  const float dmx = fmaxf(fmaxf(dsm[0], dsm[1]), fmaxf(dsm[2], dsm[3]));
  const float e0 = srci + dmx;
  const float mi = fmaxf(e0, 0.2f * e0);  // upper bound of leakyrelu scores
  const float cA = __expf(srci - mi);
  const float cB = __expf(0.2f * srci - mi);
  // 8 mask words for this row/chunk; pre-shift by kc so bit s*4 is ours.
  unsigned bl[8], bh[8];
  {
    const unsigned long long* __restrict__ pr = pk + (size_t)arow * 128 + c * 8;
    const u64x2 m0 = *(const u64x2*)(pr + 0);
    const u64x2 m1 = *(const u64x2*)(pr + 2);
    const u64x2 m2 = *(const u64x2*)(pr + 4);
    const u64x2 m3 = *(const u64x2*)(pr + 6);
    const unsigned long long mw[8] = {m0[0], m0[1], m1[0], m1[1],
                                      m2[0], m2[1], m3[0], m3[1]};
#pragma unroll
    for (int e = 0; e < 8; ++e) {
      const unsigned long long sh = mw[e] >> kc;
      bl[e] = (unsigned)sh;
      bh[e] = (unsigned)(sh >> 32);
    }
  }
  f32x4 acc0 = {0.f, 0.f, 0.f, 0.f};
  f32x4 acc1 = acc0, acc2 = acc0, acc3 = acc0;
  float sac = 0.f;
  const unsigned short* __restrict__ hb =
      HTt + (size_t)(cbase >> 5) * 2048 + l15 * 32 + kc * 8;
#pragma unroll
  for (int half = 0; half < 2; ++half) {
#pragma unroll 2
    for (int s4 = 0; s4 < 8; ++s4) {
      const int s = half * 8 + s4;
      const int jr = s * 32 + kc * 8;
      const int sh = s4 * 4;
      const f32x4 e1a = *(const f32x4*)&E1s[jr];
      const f32x4 e1b = *(const f32x4*)&E1s[jr + 4];
      const f32x4 e2a = *(const f32x4*)&E2s[jr];
      const f32x4 e2b = *(const f32x4*)&E2s[jr + 4];
      float pv[8];
#pragma unroll
      for (int e = 0; e < 8; ++e) {
        const float E1v = (e < 4) ? e1a[e & 3] : e1b[e & 3];
        const float E2v = (e < 4) ? e2a[e & 3] : e2b[e & 3];
        float p = fmaxf(cA * E1v, cB * E2v);  // exp(leaky(src+dst)-mi)
        const unsigned w = half ? bh[e] : bl[e];
        p = ((w >> sh) & 1u) ? p : 0.f;
        sac += p;
        pv[e] = p;
      }
      short8 af;
      ((unsigned*)&af)[0] = cvtpk(pv[0], pv[1]);
      ((unsigned*)&af)[1] = cvtpk(pv[2], pv[3]);
      ((unsigned*)&af)[2] = cvtpk(pv[4], pv[5]);
      ((unsigned*)&af)[3] = cvtpk(pv[6], pv[7]);
      const unsigned short* hj = hb + (size_t)s * 2048;
      const short8 bf0 = *(const short8*)(hj);
      const short8 bf1 = *(const short8*)(hj + 512);
      const short8 bf2 = *(const short8*)(hj + 1024);
      const short8 bf3 = *(const short8*)(hj + 1536);
      acc0 = __builtin_amdgcn_mfma_f32_16x16x32_bf16(af, bf0, acc0, 0, 0, 0);
      acc1 = __builtin_amdgcn_mfma_f32_16x16x32_bf16(af, bf1, acc1, 0, 0, 0);
      acc2 = __builtin_amdgcn_mfma_f32_16x16x32_bf16(af, bf2, acc2, 0, 0, 0);
      acc3 = __builtin_amdgcn_mfma_f32_16x16x32_bf16(af, bf3, acc3, 0, 0, 0);
    }
  }
  float st = sac;
  st += __shfl_xor(st, 16);
  st += __shfl_xor(st, 32);
  if (lane < 16) ps[(size_t)c * NN + arow] = st;
  const int orow = rowtile + kc * 4;  // C/D: col=lane&15, row=kc*4+v
  float* __restrict__ pb = pacc + ((size_t)c * NN + orow) * DOUT + l15;
#pragma unroll
  for (int v = 0; v < 4; ++v) {
    pb[(size_t)v * DOUT + 0] = acc0[v];
    pb[(size_t)v * DOUT + 16] = acc1[v];
    pb[(size_t)v * DOUT + 32] = acc2[v];
    pb[(size_t)v * DOUT + 48] = acc3[v];
  }
}

__global__ __launch_bounds__(256) void k_fin(const float* __restrict__ pacc,
                                             const float* __restrict__ ps,
                                             float* __restrict__ out) {
  const int idx = blockIdx.x * 256 + threadIdx.x;
  const int i = idx >> 6;
  float ss = 0.f, as = 0.f;
#pragma unroll
  for (int c = 0; c < NCH; ++c) {
    ss += ps[(size_t)c * NN + i];
    as += pacc[(size_t)c * NN * DOUT + idx];
  }
  const float v = as / ss;
  out[idx] = v > 0.f ? v : (__expf(v) - 1.f);
}

extern "C" void kernel_launch(void* const* d_in, const int* in_sizes, int n_in,
                              void* d_out, int out_size, void* d_ws,
                              size_t ws_size, hipStream_t stream) {
  const float* X = (const float*)d_in[0];
  const int* adj = (const int*)d_in[1];
  const float* W = (const float*)d_in[2];
  const float* A = (const float*)d_in[3];
  float* out = (float*)d_out;
  char* ws = (char*)d_ws;
  float* src = (float*)(ws);                                   // 32 KB
  float* dst = (float*)(ws + (32u << 10));                     // 32 KB
  float* dmax_arr = (float*)(ws + (64u << 10));                // 2 KB
  unsigned short* WTb = (unsigned short*)(ws + (128u << 10));  // 32 KB
  unsigned short* HTt = (unsigned short*)(ws + (256u << 10));  // 1 MB
  unsigned long long* pkb = (unsigned long long*)(ws + (2u << 20));  // 8 MB
  float* pacc = (float*)(ws + (16u << 20));    // NCH*2 MB = 32 MB
  float* ps = pacc + (size_t)NCH * NN * DOUT;  // NCH*32 KB
  k_prep<<<64, 256, 0, stream>>>(W, WTb);
  k_hwpack<<<128 + NN / 4, 256, 0, stream>>>(X, WTb, A, adj, src, dst,
                                             dmax_arr, HTt, pkb);
  k_att<<<dim3(NN / 64, NCH), 256, 0, stream>>>(pkb, src, dst, dmax_arr, HTt,
                                                pacc, ps);
  k_fin<<<NN * DOUT / 256, 256, 0, stream>>>(pacc, ps, out);
}

// Round 7
// 112.517 us; speedup vs baseline: 1.4053x; 1.0573x over previous
//
#include <hip/hip_runtime.h>
#include <hip/hip_bf16.h>

#define NN 8192
#define DIN 256
#define DOUT 64
#define NCH 16
#define CHJ (NN / NCH)  // 512

typedef __attribute__((ext_vector_type(4))) float f32x4;
typedef __attribute__((ext_vector_type(4))) int i32x4;
typedef __attribute__((ext_vector_type(8))) short short8;
typedef __attribute__((ext_vector_type(2))) unsigned long long u64x2;

__device__ __forceinline__ unsigned short f2bf(float f) {
  unsigned u = __float_as_uint(f);
  u += 0x7fffu + ((u >> 16) & 1u);
  return (unsigned short)(u >> 16);
}
__device__ __forceinline__ unsigned pk2bf(float lo, float hi) {
  return (unsigned)f2bf(lo) | ((unsigned)f2bf(hi) << 16);
}
__device__ __forceinline__ unsigned cvtpk(float lo, float hi) {
  unsigned r;
  asm("v_cvt_pk_bf16_f32 %0, %1, %2" : "=v"(r) : "v"(lo), "v"(hi));
  return r;
}

// WTb[d][k] = bf16(W[k][d]); grid 64 x 256
__global__ __launch_bounds__(256) void k_prep(const float* __restrict__ W,
                                              unsigned short* __restrict__ WTb) {
  const int i = blockIdx.x * 256 + threadIdx.x;
  const int d = i >> 8, k = i & 255;
  WTb[i] = f2bf(W[k * DOUT + d]);
}

// blocks [0,128): h=X@W via MFMA -> src/dst/dmax_arr/HTt. blocks [128,2176): bitpack adj.
__global__ __launch_bounds__(256) void k_hwpack(
    const float* __restrict__ X, const unsigned short* __restrict__ WTb,
    const float* __restrict__ A, const int* __restrict__ adj,
    float* __restrict__ src, float* __restrict__ dst,
    float* __restrict__ dmax_arr, unsigned short* __restrict__ HTt,
    unsigned long long* __restrict__ pk) {
  const int tid = threadIdx.x;
  const int wid = tid >> 6, lane = tid & 63;
  if (blockIdx.x >= 128) {
    // ---- pack: one adj row per wave; word w = i*8 + (j&7), bit = (j>>3)&63
    const int row = (blockIdx.x - 128) * 4 + wid;
    const i32x4* __restrict__ ap = (const i32x4*)(adj + (size_t)row * NN);
    unsigned long long* __restrict__ pr = pk + (size_t)row * 128;
#pragma unroll 4
    for (int i = 0; i < 16; ++i) {
      const i32x4 v0 = ap[i * 128 + lane * 2];
      const i32x4 v1 = ap[i * 128 + lane * 2 + 1];
      const unsigned long long b0 = __ballot(v0[0] > 0);
      const unsigned long long b1 = __ballot(v0[1] > 0);
      const unsigned long long b2 = __ballot(v0[2] > 0);
      const unsigned long long b3 = __ballot(v0[3] > 0);
      const unsigned long long b4 = __ballot(v1[0] > 0);
      const unsigned long long b5 = __ballot(v1[1] > 0);
      const unsigned long long b6 = __ballot(v1[2] > 0);
      const unsigned long long b7 = __ballot(v1[3] > 0);
      if (lane == 0) {
        u64x2 s0, s1, s2, s3;
        s0[0] = b0; s0[1] = b1; s1[0] = b2; s1[1] = b3;
        s2[0] = b4; s2[1] = b5; s3[0] = b6; s3[1] = b7;
        *(u64x2*)(pr + i * 8 + 0) = s0;
        *(u64x2*)(pr + i * 8 + 2) = s1;
        *(u64x2*)(pr + i * 8 + 4) = s2;
        *(u64x2*)(pr + i * 8 + 6) = s3;
      }
    }
    return;
  }
  // ---- hw: 16 rows per wave via mfma 16x16x32 ----
  const int l15 = lane & 15, kc = lane >> 4;
  const int rt = blockIdx.x * 64 + wid * 16;
  const float* __restrict__ xr = X + (size_t)(rt + l15) * DIN + kc * 8;
  const unsigned short* __restrict__ wb = WTb + (size_t)l15 * DIN + kc * 8;
  f32x4 acc0 = {0.f, 0.f, 0.f, 0.f};
  f32x4 acc1 = acc0, acc2 = acc0, acc3 = acc0;
#pragma unroll
  for (int ks = 0; ks < 8; ++ks) {
    const f32x4 x0 = *(const f32x4*)(xr + ks * 32);
    const f32x4 x1 = *(const f32x4*)(xr + ks * 32 + 4);
    short8 af;
    ((unsigned*)&af)[0] = pk2bf(x0[0], x0[1]);
    ((unsigned*)&af)[1] = pk2bf(x0[2], x0[3]);
    ((unsigned*)&af)[2] = pk2bf(x1[0], x1[1]);
    ((unsigned*)&af)[3] = pk2bf(x1[2], x1[3]);
    const short8 b0 = *(const short8*)(wb + ks * 32);
    const short8 b1 = *(const short8*)(wb + 16 * DIN + ks * 32);
    const short8 b2 = *(const short8*)(wb + 32 * DIN + ks * 32);
    const short8 b3 = *(const short8*)(wb + 48 * DIN + ks * 32);
    acc0 = __builtin_amdgcn_mfma_f32_16x16x32_bf16(af, b0, acc0, 0, 0, 0);
    acc1 = __builtin_amdgcn_mfma_f32_16x16x32_bf16(af, b1, acc1, 0, 0, 0);
    acc2 = __builtin_amdgcn_mfma_f32_16x16x32_bf16(af, b2, acc2, 0, 0, 0);
    acc3 = __builtin_amdgcn_mfma_f32_16x16x32_bf16(af, b3, acc3, 0, 0, 0);
  }
  const float as0 = A[l15], as1 = A[16 + l15], as2 = A[32 + l15],
              as3 = A[48 + l15];
  const float ad0 = A[64 + l15], ad1 = A[80 + l15], ad2 = A[96 + l15],
              ad3 = A[112 + l15];
  float dm = -1e30f;
#pragma unroll
  for (int v = 0; v < 4; ++v) {
    float sv = acc0[v] * as0 + acc1[v] * as1 + acc2[v] * as2 + acc3[v] * as3;
    float dv = acc0[v] * ad0 + acc1[v] * ad1 + acc2[v] * ad2 + acc3[v] * ad3;
#pragma unroll
    for (int m = 1; m < 16; m <<= 1) {
      sv += __shfl_xor(sv, m);
      dv += __shfl_xor(dv, m);
    }
    if (l15 == 0) {
      src[rt + kc * 4 + v] = sv;
      dst[rt + kc * 4 + v] = dv;
    }
    dm = fmaxf(dm, dv);
  }
  dm = fmaxf(dm, __shfl_xor(dm, 16));
  dm = fmaxf(dm, __shfl_xor(dm, 32));
  if (lane == 0) dmax_arr[blockIdx.x * 4 + wid] = dm;
  // HTt[jb][n][l15][jin] = bf16(h[jb*32+jin][n*16+l15])
  unsigned short* __restrict__ hs =
      HTt + (size_t)(rt >> 5) * 2048 + l15 * 32 + (rt & 16) + kc * 4;
  *(unsigned*)(hs + 0 * 512) = pk2bf(acc0[0], acc0[1]);
  *(unsigned*)(hs + 0 * 512 + 2) = pk2bf(acc0[2], acc0[3]);
  *(unsigned*)(hs + 1 * 512) = pk2bf(acc1[0], acc1[1]);
  *(unsigned*)(hs + 1 * 512 + 2) = pk2bf(acc1[2], acc1[3]);
  *(unsigned*)(hs + 2 * 512) = pk2bf(acc2[0], acc2[1]);
  *(unsigned*)(hs + 2 * 512 + 2) = pk2bf(acc2[2], acc2[3]);
  *(unsigned*)(hs + 3 * 512) = pk2bf(acc3[0], acc3[1]);
  *(unsigned*)(hs + 3 * 512 + 2) = pk2bf(acc3[2], acc3[3]);
}

// Fused masked-softmax-numerator @ H via MFMA on packed bits; exp via E-tables.
__global__ __launch_bounds__(256) void k_att(
    const unsigned long long* __restrict__ pk, const float* __restrict__ src,
    const float* __restrict__ dst, const float* __restrict__ dmax_arr,
    const unsigned short* __restrict__ HTt, float* __restrict__ pacc,
    float* __restrict__ ps) {
  __shared__ float E1s[CHJ], E2s[CHJ];
  __shared__ float dsm[4];
  const int tid = threadIdx.x;
  const int wid = tid >> 6, lane = tid & 63;
  const int l15 = lane & 15, kc = lane >> 4;
  const int rowtile = blockIdx.x * 64 + wid * 16;
  const int c = blockIdx.y;
  const int cbase = c * CHJ;
  {
    const float2 dv2 = *(const float2*)(dst + cbase + tid * 2);
    E1s[tid * 2] = __expf(dv2.x);
    E1s[tid * 2 + 1] = __expf(dv2.y);
    E2s[tid * 2] = __expf(0.2f * dv2.x);
    E2s[tid * 2 + 1] = __expf(0.2f * dv2.y);
    float dm0 = fmaxf(dmax_arr[tid], dmax_arr[tid + 256]);
#pragma unroll
    for (int m = 1; m < 64; m <<= 1) dm0 = fmaxf(dm0, __shfl_xor(dm0, m));
    if (lane == 0) dsm[wid] = dm0;
  }
  __syncthreads();
  const int arow = rowtile + l15;
  const float srci = src[arow];
  const float dmx = fmaxf(fmaxf(dsm[0], dsm[1]), fmaxf(dsm[2], dsm[3]));
  const float e0 = srci + dmx;
  const float mi = fmaxf(e0, 0.2f * e0);  // upper bound of leakyrelu scores
  const float cA = __expf(srci - mi);
  const float cB = __expf(0.2f * srci - mi);
  // 8 mask words for this row/chunk; pre-shift by kc so bit s*4 is ours.
  unsigned bl[8], bh[8];
  {
    const unsigned long long* __restrict__ pr = pk + (size_t)arow * 128 + c * 8;
    const u64x2 m0 = *(const u64x2*)(pr + 0);
    const u64x2 m1 = *(const u64x2*)(pr + 2);
    const u64x2 m2 = *(const u64x2*)(pr + 4);
    const u64x2 m3 = *(const u64x2*)(pr + 6);
    const unsigned long long mw[8] = {m0[0], m0[1], m1[0], m1[1],
                                      m2[0], m2[1], m3[0], m3[1]};
#pragma unroll
    for (int e = 0; e < 8; ++e) {
      const unsigned long long sh = mw[e] >> kc;
      bl[e] = (unsigned)sh;
      bh[e] = (unsigned)(sh >> 32);
    }
  }
  f32x4 acc0 = {0.f, 0.f, 0.f, 0.f};
  f32x4 acc1 = acc0, acc2 = acc0, acc3 = acc0;
  float sac = 0.f;
  const unsigned short* __restrict__ hb =
      HTt + (size_t)(cbase >> 5) * 2048 + l15 * 32 + kc * 8;
#pragma unroll
  for (int half = 0; half < 2; ++half) {
#pragma unroll 2
    for (int s4 = 0; s4 < 8; ++s4) {
      const int s = half * 8 + s4;
      const int jr = s * 32 + kc * 8;
      const int sh = s4 * 4;
      const f32x4 e1a = *(const f32x4*)&E1s[jr];
      const f32x4 e1b = *(const f32x4*)&E1s[jr + 4];
      const f32x4 e2a = *(const f32x4*)&E2s[jr];
      const f32x4 e2b = *(const f32x4*)&E2s[jr + 4];
      float pv[8];
#pragma unroll
      for (int e = 0; e < 8; ++e) {
        const float E1v = (e < 4) ? e1a[e & 3] : e1b[e & 3];
        const float E2v = (e < 4) ? e2a[e & 3] : e2b[e & 3];
        float p = fmaxf(cA * E1v, cB * E2v);  // exp(leaky(src+dst)-mi)
        const unsigned w = half ? bh[e] : bl[e];
        p = ((w >> sh) & 1u) ? p : 0.f;
        sac += p;
        pv[e] = p;
      }
      short8 af;
      ((unsigned*)&af)[0] = cvtpk(pv[0], pv[1]);
      ((unsigned*)&af)[1] = cvtpk(pv[2], pv[3]);
      ((unsigned*)&af)[2] = cvtpk(pv[4], pv[5]);
      ((unsigned*)&af)[3] = cvtpk(pv[6], pv[7]);
      const unsigned short* hj = hb + (size_t)s * 2048;
      const short8 bf0 = *(const short8*)(hj);
      const short8 bf1 = *(const short8*)(hj + 512);
      const short8 bf2 = *(const short8*)(hj + 1024);
      const short8 bf3 = *(const short8*)(hj + 1536);
      acc0 = __builtin_amdgcn_mfma_f32_16x16x32_bf16(af, bf0, acc0, 0, 0, 0);
      acc1 = __builtin_amdgcn_mfma_f32_16x16x32_bf16(af, bf1, acc1, 0, 0, 0);
      acc2 = __builtin_amdgcn_mfma_f32_16x16x32_bf16(af, bf2, acc2, 0, 0, 0);
      acc3 = __builtin_amdgcn_mfma_f32_16x16x32_bf16(af, bf3, acc3, 0, 0, 0);
    }
  }
  float st = sac;
  st += __shfl_xor(st, 16);
  st += __shfl_xor(st, 32);
  if (lane < 16) ps[(size_t)c * NN + arow] = st;
  const int orow = rowtile + kc * 4;  // C/D: col=lane&15, row=kc*4+v
  float* __restrict__ pb = pacc + ((size_t)c * NN + orow) * DOUT + l15;
#pragma unroll
  for (int v = 0; v < 4; ++v) {
    pb[(size_t)v * DOUT + 0] = acc0[v];
    pb[(size_t)v * DOUT + 16] = acc1[v];
    pb[(size_t)v * DOUT + 32] = acc2[v];
    pb[(size_t)v * DOUT + 48] = acc3[v];
  }
}

__global__ __launch_bounds__(256) void k_fin(const float* __restrict__ pacc,
                                             const float* __restrict__ ps,
                                             float* __restrict__ out) {
  const int idx = blockIdx.x * 256 + threadIdx.x;
  const int i = idx >> 6;
  float ss = 0.f, as = 0.f;
#pragma unroll
  for (int c = 0; c < NCH; ++c) {
    ss += ps[(size_t)c * NN + i];
    as += pacc[(size_t)c * NN * DOUT + idx];
  }
  const float v = as / ss;
  out[idx] = v > 0.f ? v : (__expf(v) - 1.f);
}

extern "C" void kernel_launch(void* const* d_in, const int* in_sizes, int n_in,
                              void* d_out, int out_size, void* d_ws,
                              size_t ws_size, hipStream_t stream) {
  const float* X = (const float*)d_in[0];
  const int* adj = (const int*)d_in[1];
  const float* W = (const float*)d_in[2];
  const float* A = (const float*)d_in[3];
  float* out = (float*)d_out;
  char* ws = (char*)d_ws;
  float* src = (float*)(ws);                                   // 32 KB
  float* dst = (float*)(ws + (32u << 10));                     // 32 KB
  float* dmax_arr = (float*)(ws + (64u << 10));                // 2 KB
  unsigned short* WTb = (unsigned short*)(ws + (128u << 10));  // 32 KB
  unsigned short* HTt = (unsigned short*)(ws + (256u << 10));  // 1 MB
  unsigned long long* pkb = (unsigned long long*)(ws + (2u << 20));  // 8 MB
  float* pacc = (float*)(ws + (16u << 20));    // NCH*2 MB = 32 MB
  float* ps = pacc + (size_t)NCH * NN * DOUT;  // NCH*32 KB
  k_prep<<<64, 256, 0, stream>>>(W, WTb);
  k_hwpack<<<128 + NN / 4, 256, 0, stream>>>(X, WTb, A, adj, src, dst,
                                             dmax_arr, HTt, pkb);
  k_att<<<dim3(NN / 64, NCH), 256, 0, stream>>>(pkb, src, dst, dmax_arr, HTt,
                                                pacc, ps);
  k_fin<<<NN * DOUT / 256, 256, 0, stream>>>(pacc, ps, out);
}

// Round 8
// 106.260 us; speedup vs baseline: 1.4880x; 1.0589x over previous
//
#include <hip/hip_runtime.h>
#include <hip/hip_bf16.h>

#define NN 8192
#define DIN 256
#define DOUT 64
#define NCH 16
#define CHJ (NN / NCH)  // 512

typedef __attribute__((ext_vector_type(4))) float f32x4;
typedef __attribute__((ext_vector_type(4))) int i32x4;
typedef __attribute__((ext_vector_type(8))) short short8;
typedef __attribute__((ext_vector_type(2))) unsigned long long u64x2;

__device__ __forceinline__ unsigned short f2bf(float f) {
  unsigned u = __float_as_uint(f);
  u += 0x7fffu + ((u >> 16) & 1u);
  return (unsigned short)(u >> 16);
}
__device__ __forceinline__ unsigned pk2bf(float lo, float hi) {
  return (unsigned)f2bf(lo) | ((unsigned)f2bf(hi) << 16);
}
__device__ __forceinline__ unsigned cvtpk(float lo, float hi) {
  unsigned r;
  asm("v_cvt_pk_bf16_f32 %0, %1, %2" : "=v"(r) : "v"(lo), "v"(hi));
  return r;
}

// WTb[d][k] = bf16(W[k][d]); grid 64 x 256
__global__ __launch_bounds__(256) void k_prep(const float* __restrict__ W,
                                              unsigned short* __restrict__ WTb) {
  const int i = blockIdx.x * 256 + threadIdx.x;
  const int d = i >> 8, k = i & 255;
  WTb[i] = f2bf(W[k * DOUT + d]);
}

// blocks [0,128): h=X@W via MFMA -> src/dst/dmax_arr/HTt. blocks [128,2176): bitpack adj.
// pack layout: word w = i*8+e; e<4: bit l <-> adj[i*512 + 4l + e];
//              e>=4: bit l <-> adj[i*512 + 256 + 4l + (e-4)].
__global__ __launch_bounds__(256) void k_hwpack(
    const float* __restrict__ X, const unsigned short* __restrict__ WTb,
    const float* __restrict__ A, const int* __restrict__ adj,
    float* __restrict__ src, float* __restrict__ dst,
    float* __restrict__ dmax_arr, unsigned short* __restrict__ HTt,
    unsigned long long* __restrict__ pk) {
  const int tid = threadIdx.x;
  const int wid = tid >> 6, lane = tid & 63;
  if (blockIdx.x >= 128) {
    // ---- pack: one adj row per wave; contiguous 1KB per load instruction.
    const int row = (blockIdx.x - 128) * 4 + wid;
    const i32x4* __restrict__ ap = (const i32x4*)(adj + (size_t)row * NN);
    unsigned long long* __restrict__ pr = pk + (size_t)row * 128;
    const int sel = lane >> 2;
    const bool c1 = (lane & 1) != 0, c2 = (lane & 2) != 0;
    unsigned long long my0 = 0ull, my1 = 0ull;
#pragma unroll 8
    for (int i = 0; i < 16; ++i) {
      const i32x4 v0 = ap[i * 128 + lane];
      const i32x4 v1 = ap[i * 128 + 64 + lane];
      const unsigned long long b0 = __ballot(v0[0] > 0);
      const unsigned long long b1 = __ballot(v0[1] > 0);
      const unsigned long long b2 = __ballot(v0[2] > 0);
      const unsigned long long b3 = __ballot(v0[3] > 0);
      const unsigned long long b4 = __ballot(v1[0] > 0);
      const unsigned long long b5 = __ballot(v1[1] > 0);
      const unsigned long long b6 = __ballot(v1[2] > 0);
      const unsigned long long b7 = __ballot(v1[3] > 0);
      // lane keeps words 2*lane, 2*lane+1 (word k = i*8+e kept by lane i*4+(e>>1))
      const unsigned long long t0 = c2 ? (c1 ? b6 : b4) : (c1 ? b2 : b0);
      const unsigned long long t1 = c2 ? (c1 ? b7 : b5) : (c1 ? b3 : b1);
      if (sel == i) {
        my0 = t0;
        my1 = t1;
      }
    }
    u64x2 st;
    st[0] = my0;
    st[1] = my1;
    *(u64x2*)(pr + lane * 2) = st;  // one coalesced 1KB store per row
    return;
  }
  // ---- hw: 16 rows per wave via mfma 16x16x32 ----
  const int l15 = lane & 15, kc = lane >> 4;
  const int rt = blockIdx.x * 64 + wid * 16;
  const float* __restrict__ xr = X + (size_t)(rt + l15) * DIN + kc * 8;
  const unsigned short* __restrict__ wb = WTb + (size_t)l15 * DIN + kc * 8;
  f32x4 acc0 = {0.f, 0.f, 0.f, 0.f};
  f32x4 acc1 = acc0, acc2 = acc0, acc3 = acc0;
#pragma unroll
  for (int ks = 0; ks < 8; ++ks) {
    const f32x4 x0 = *(const f32x4*)(xr + ks * 32);
    const f32x4 x1 = *(const f32x4*)(xr + ks * 32 + 4);
    short8 af;
    ((unsigned*)&af)[0] = pk2bf(x0[0], x0[1]);
    ((unsigned*)&af)[1] = pk2bf(x0[2], x0[3]);
    ((unsigned*)&af)[2] = pk2bf(x1[0], x1[1]);
    ((unsigned*)&af)[3] = pk2bf(x1[2], x1[3]);
    const short8 b0 = *(const short8*)(wb + ks * 32);
    const short8 b1 = *(const short8*)(wb + 16 * DIN + ks * 32);
    const short8 b2 = *(const short8*)(wb + 32 * DIN + ks * 32);
    const short8 b3 = *(const short8*)(wb + 48 * DIN + ks * 32);
    acc0 = __builtin_amdgcn_mfma_f32_16x16x32_bf16(af, b0, acc0, 0, 0, 0);
    acc1 = __builtin_amdgcn_mfma_f32_16x16x32_bf16(af, b1, acc1, 0, 0, 0);
    acc2 = __builtin_amdgcn_mfma_f32_16x16x32_bf16(af, b2, acc2, 0, 0, 0);
    acc3 = __builtin_amdgcn_mfma_f32_16x16x32_bf16(af, b3, acc3, 0, 0, 0);
  }
  const float as0 = A[l15], as1 = A[16 + l15], as2 = A[32 + l15],
              as3 = A[48 + l15];
  const float ad0 = A[64 + l15], ad1 = A[80 + l15], ad2 = A[96 + l15],
              ad3 = A[112 + l15];
  float dm = -1e30f;
#pragma unroll
  for (int v = 0; v < 4; ++v) {
    float sv = acc0[v] * as0 + acc1[v] * as1 + acc2[v] * as2 + acc3[v] * as3;
    float dv = acc0[v] * ad0 + acc1[v] * ad1 + acc2[v] * ad2 + acc3[v] * ad3;
#pragma unroll
    for (int m = 1; m < 16; m <<= 1) {
      sv += __shfl_xor(sv, m);
      dv += __shfl_xor(dv, m);
    }
    if (l15 == 0) {
      src[rt + kc * 4 + v] = sv;
      dst[rt + kc * 4 + v] = dv;
    }
    dm = fmaxf(dm, dv);
  }
  dm = fmaxf(dm, __shfl_xor(dm, 16));
  dm = fmaxf(dm, __shfl_xor(dm, 32));
  if (lane == 0) dmax_arr[blockIdx.x * 4 + wid] = dm;
  // HTt[jb][n][l15][jin] = bf16(h[jb*32+jin][n*16+l15])
  unsigned short* __restrict__ hs =
      HTt + (size_t)(rt >> 5) * 2048 + l15 * 32 + (rt & 16) + kc * 4;
  *(unsigned*)(hs + 0 * 512) = pk2bf(acc0[0], acc0[1]);
  *(unsigned*)(hs + 0 * 512 + 2) = pk2bf(acc0[2], acc0[3]);
  *(unsigned*)(hs + 1 * 512) = pk2bf(acc1[0], acc1[1]);
  *(unsigned*)(hs + 1 * 512 + 2) = pk2bf(acc1[2], acc1[3]);
  *(unsigned*)(hs + 2 * 512) = pk2bf(acc2[0], acc2[1]);
  *(unsigned*)(hs + 2 * 512 + 2) = pk2bf(acc2[2], acc2[3]);
  *(unsigned*)(hs + 3 * 512) = pk2bf(acc3[0], acc3[1]);
  *(unsigned*)(hs + 3 * 512 + 2) = pk2bf(acc3[2], acc3[3]);
}

// Fused masked-softmax-numerator @ H via MFMA on packed bits; exp via E-tables.
__global__ __launch_bounds__(256) void k_att(
    const unsigned long long* __restrict__ pk, const float* __restrict__ src,
    const float* __restrict__ dst, const float* __restrict__ dmax_arr,
    const unsigned short* __restrict__ HTt, float* __restrict__ pacc,
    float* __restrict__ ps) {
  __shared__ float E1s[CHJ], E2s[CHJ];
  __shared__ float dsm[4];
  const int tid = threadIdx.x;
  const int wid = tid >> 6, lane = tid & 63;
  const int l15 = lane & 15, kc = lane >> 4;
  const int rowtile = blockIdx.x * 64 + wid * 16;
  const int c = blockIdx.y;
  const int cbase = c * CHJ;
  {
    const float2 dv2 = *(const float2*)(dst + cbase + tid * 2);
    E1s[tid * 2] = __expf(dv2.x);
    E1s[tid * 2 + 1] = __expf(dv2.y);
    E2s[tid * 2] = __expf(0.2f * dv2.x);
    E2s[tid * 2 + 1] = __expf(0.2f * dv2.y);
    float dm0 = fmaxf(dmax_arr[tid], dmax_arr[tid + 256]);
#pragma unroll
    for (int m = 1; m < 64; m <<= 1) dm0 = fmaxf(dm0, __shfl_xor(dm0, m));
    if (lane == 0) dsm[wid] = dm0;
  }
  __syncthreads();
  const int arow = rowtile + l15;
  const float srci = src[arow];
  const float dmx = fmaxf(fmaxf(dsm[0], dsm[1]), fmaxf(dsm[2], dsm[3]));
  const float e0 = srci + dmx;
  const float mi = fmaxf(e0, 0.2f * e0);  // upper bound of leakyrelu scores
  const float cA = __expf(srci - mi);
  const float cB = __expf(0.2f * srci - mi);
  // 8 mask words for this row/chunk, pre-shifted by kc*2.
  // word e (e<4): bit (j>>2) <-> j = 4l+e (j<256); e>=4: j = 256+4l+(e-4).
  unsigned lo[8], hi[8];
  {
    const unsigned long long* __restrict__ pr = pk + (size_t)arow * 128 + c * 8;
    const u64x2 m0 = *(const u64x2*)(pr + 0);
    const u64x2 m1 = *(const u64x2*)(pr + 2);
    const u64x2 m2 = *(const u64x2*)(pr + 4);
    const u64x2 m3 = *(const u64x2*)(pr + 6);
    const unsigned long long mw[8] = {m0[0], m0[1], m1[0], m1[1],
                                      m2[0], m2[1], m3[0], m3[1]};
#pragma unroll
    for (int e = 0; e < 8; ++e) {
      const unsigned long long sh = mw[e] >> (kc * 2);
      lo[e] = (unsigned)sh;
      hi[e] = (unsigned)(sh >> 32);
    }
  }
  f32x4 acc0 = {0.f, 0.f, 0.f, 0.f};
  f32x4 acc1 = acc0, acc2 = acc0, acc3 = acc0;
  float sac = 0.f;
  const unsigned short* __restrict__ hb =
      HTt + (size_t)(cbase >> 5) * 2048 + l15 * 32 + kc * 8;
#pragma unroll
  for (int h = 0; h < 2; ++h) {
#pragma unroll
    for (int q = 0; q < 2; ++q) {
#pragma unroll 2
      for (int s4 = 0; s4 < 4; ++s4) {
        const int s = h * 8 + q * 4 + s4;
        const int jr = s * 32 + kc * 8;
        const f32x4 e1a = *(const f32x4*)&E1s[jr];
        const f32x4 e1b = *(const f32x4*)&E1s[jr + 4];
        const f32x4 e2a = *(const f32x4*)&E2s[jr];
        const f32x4 e2b = *(const f32x4*)&E2s[jr + 4];
        float pv[8];
#pragma unroll
        for (int e = 0; e < 8; ++e) {
          const float E1v = (e < 4) ? e1a[e & 3] : e1b[e & 3];
          const float E2v = (e < 4) ? e2a[e & 3] : e2b[e & 3];
          float p = fmaxf(cA * E1v, cB * E2v);  // exp(leaky(src+dst)-mi)
          const unsigned w = h ? (q ? hi[4 + (e & 3)] : lo[4 + (e & 3)])
                               : (q ? hi[e & 3] : lo[e & 3]);
          p = ((w >> (s4 * 8 + (e >> 2))) & 1u) ? p : 0.f;
          sac += p;
          pv[e] = p;
        }
        short8 af;
        ((unsigned*)&af)[0] = cvtpk(pv[0], pv[1]);
        ((unsigned*)&af)[1] = cvtpk(pv[2], pv[3]);
        ((unsigned*)&af)[2] = cvtpk(pv[4], pv[5]);
        ((unsigned*)&af)[3] = cvtpk(pv[6], pv[7]);
        const unsigned short* hj = hb + (size_t)s * 2048;
        const short8 bf0 = *(const short8*)(hj);
        const short8 bf1 = *(const short8*)(hj + 512);
        const short8 bf2 = *(const short8*)(hj + 1024);
        const short8 bf3 = *(const short8*)(hj + 1536);
        acc0 = __builtin_amdgcn_mfma_f32_16x16x32_bf16(af, bf0, acc0, 0, 0, 0);
        acc1 = __builtin_amdgcn_mfma_f32_16x16x32_bf16(af, bf1, acc1, 0, 0, 0);
        acc2 = __builtin_amdgcn_mfma_f32_16x16x32_bf16(af, bf2, acc2, 0, 0, 0);
        acc3 = __builtin_amdgcn_mfma_f32_16x16x32_bf16(af, bf3, acc3, 0, 0, 0);
      }
    }
  }
  float st = sac;
  st += __shfl_xor(st, 16);
  st += __shfl_xor(st, 32);
  if (lane < 16) ps[(size_t)c * NN + arow] = st;
  const int orow = rowtile + kc * 4;  // C/D: col=lane&15, row=kc*4+v
  float* __restrict__ pb = pacc + ((size_t)c * NN + orow) * DOUT + l15;
#pragma unroll
  for (int v = 0; v < 4; ++v) {
    pb[(size_t)v * DOUT + 0] = acc0[v];
    pb[(size_t)v * DOUT + 16] = acc1[v];
    pb[(size_t)v * DOUT + 32] = acc2[v];
    pb[(size_t)v * DOUT + 48] = acc3[v];
  }
}

__global__ __launch_bounds__(256) void k_fin(const float* __restrict__ pacc,
                                             const float* __restrict__ ps,
                                             float* __restrict__ out) {
  const int idx = blockIdx.x * 256 + threadIdx.x;
  const int i = idx >> 6;
  float ss = 0.f, as = 0.f;
#pragma unroll
  for (int c = 0; c < NCH; ++c) {
    ss += ps[(size_t)c * NN + i];
    as += pacc[(size_t)c * NN * DOUT + idx];
  }
  const float v = as / ss;
  out[idx] = v > 0.f ? v : (__expf(v) - 1.f);
}

extern "C" void kernel_launch(void* const* d_in, const int* in_sizes, int n_in,
                              void* d_out, int out_size, void* d_ws,
                              size_t ws_size, hipStream_t stream) {
  const float* X = (const float*)d_in[0];
  const int* adj = (const int*)d_in[1];
  const float* W = (const float*)d_in[2];
  const float* A = (const float*)d_in[3];
  float* out = (float*)d_out;
  char* ws = (char*)d_ws;
  float* src = (float*)(ws);                                   // 32 KB
  float* dst = (float*)(ws + (32u << 10));                     // 32 KB
  float* dmax_arr = (float*)(ws + (64u << 10));                // 2 KB
  unsigned short* WTb = (unsigned short*)(ws + (128u << 10));  // 32 KB
  unsigned short* HTt = (unsigned short*)(ws + (256u << 10));  // 1 MB
  unsigned long long* pkb = (unsigned long long*)(ws + (2u << 20));  // 8 MB
  float* pacc = (float*)(ws + (16u << 20));    // NCH*2 MB = 32 MB
  float* ps = pacc + (size_t)NCH * NN * DOUT;  // NCH*32 KB
  k_prep<<<64, 256, 0, stream>>>(W, WTb);
  k_hwpack<<<128 + NN / 4, 256, 0, stream>>>(X, WTb, A, adj, src, dst,
                                             dmax_arr, HTt, pkb);
  k_att<<<dim3(NN / 64, NCH), 256, 0, stream>>>(pkb, src, dst, dmax_arr, HTt,
                                                pacc, ps);
  k_fin<<<NN * DOUT / 256, 256, 0, stream>>>(pacc, ps, out);
}